// Round 6
// baseline (243.297 us; speedup 1.0000x reference)
//
#include <hip/hip_runtime.h>
#include <cstddef>
#include <cstdint>

#define CCH 256   // channels
#define DQK 32    // q/k channels
#define NPX 4096  // H*W
#define BQ  32    // query tile per block
#define BM  64    // key tile per iteration
#define NB  4     // batch

typedef __attribute__((ext_vector_type(8))) short bf16x8;   // 8 bf16 = 4 VGPR (MFMA A/B frag)
typedef __attribute__((ext_vector_type(4))) float f32x4;    // MFMA C/D frag
typedef __attribute__((ext_vector_type(4))) unsigned int u32x4;

__device__ inline unsigned short f2bf(float f) {            // RNE float->bf16
    unsigned u = __builtin_bit_cast(unsigned, f);
    u += 0x7FFFu + ((u >> 16) & 1u);
    return (unsigned short)(u >> 16);
}

// ---------------------------------------------------------------------------
// Fused q/k/v 1x1-conv projection -> bf16 outputs in ws:
//   qT: [NB][NPX][32] bf16   (transposed: row n, cols d — MFMA B-frag friendly)
//   kT: [NB][NPX][32] bf16   (row m, cols d — MFMA A-frag friendly)
//   v : [NB][CCH][NPX] bf16  (row c, cols m — MFMA A-frag friendly)
// Block: one batch, 16 output channels, 1024 pixels (4/thread).
// ---------------------------------------------------------------------------
__global__ __launch_bounds__(256) void proj_kernel(
    const float* __restrict__ x,
    const float* __restrict__ Wq, const float* __restrict__ bq,
    const float* __restrict__ Wk, const float* __restrict__ bk,
    const float* __restrict__ Wv, const float* __restrict__ bv,
    unsigned short* __restrict__ ws)
{
    const int tid = threadIdx.x;
    const int b   = blockIdx.z;
    const int o0  = blockIdx.y * 16;
    const int nb  = blockIdx.x * 1024 + tid * 4;

    const float* Wbase;
    const float* bbase;
    if (o0 < 32)      { Wbase = Wq + o0 * CCH;        bbase = bq + o0; }
    else if (o0 < 64) { Wbase = Wk + (o0 - 32) * CCH; bbase = bk + (o0 - 32); }
    else              { Wbase = Wv + (o0 - 64) * CCH; bbase = bv + (o0 - 64); }

    float4 acc[16];
#pragma unroll
    for (int ol = 0; ol < 16; ++ol) {
        float bb = bbase[ol];
        acc[ol] = make_float4(bb, bb, bb, bb);
    }

    const float* xp = x + ((size_t)b * CCH) * NPX + nb;
#pragma unroll 4
    for (int c = 0; c < CCH; ++c) {
        float4 x4 = *(const float4*)(xp + (size_t)c * NPX);
#pragma unroll
        for (int ol = 0; ol < 16; ++ol) {
            float w = Wbase[ol * CCH + c];
            acc[ol].x += w * x4.x;
            acc[ol].y += w * x4.y;
            acc[ol].z += w * x4.z;
            acc[ol].w += w * x4.w;
        }
    }

    if (o0 < 64) {
        // transposed bf16 store: rows n = nb..nb+3, cols col0..col0+15 of [n][32]
        unsigned short* dstT = ws + ((o0 < 32) ? (size_t)0 : (size_t)NB * NPX * 32);
        const int col0 = o0 & 16;
        unsigned short* base = dstT + ((size_t)b * NPX + nb) * 32 + col0;
#pragma unroll
        for (int p = 0; p < 4; ++p) {
            unsigned u[8];
#pragma unroll
            for (int h = 0; h < 8; ++h) {
                const float* a0 = (const float*)&acc[2 * h];
                const float* a1 = (const float*)&acc[2 * h + 1];
                u[h] = (unsigned)f2bf(a0[p]) | ((unsigned)f2bf(a1[p]) << 16);
            }
            u32x4* dp = (u32x4*)(base + (size_t)p * 32);
            dp[0] = (u32x4){u[0], u[1], u[2], u[3]};
            dp[1] = (u32x4){u[4], u[5], u[6], u[7]};
        }
    } else {
        unsigned short* vbase = ws + (size_t)2 * NB * NPX * 32;
        const int c0 = o0 - 64;
#pragma unroll
        for (int ol = 0; ol < 16; ++ol) {
            unsigned lo = (unsigned)f2bf(acc[ol].x) | ((unsigned)f2bf(acc[ol].y) << 16);
            unsigned hi = (unsigned)f2bf(acc[ol].z) | ((unsigned)f2bf(acc[ol].w) << 16);
            uint2* dp = (uint2*)(vbase + ((size_t)(b * CCH + c0 + ol)) * NPX + nb);
            *dp = make_uint2(lo, hi);
        }
    }
}

// ---------------------------------------------------------------------------
// Flash attention, bf16 MFMA. Block: batch b x 32-query tile, 4 waves.
// Per 64-key tile: E^T = mfma(kT-frag, qT-frag) -> LDS fp32; softmax (8 lanes
// per query row, online m/l); P bf16 -> LDS (XOR-swizzled); PV = mfma(v-frag,
// P-frag) into f32x4 accs (wave w owns channels [w*64, w*64+64)).
// ---------------------------------------------------------------------------
__global__ __launch_bounds__(256) void attn_kernel(
    const unsigned short* __restrict__ qT, const unsigned short* __restrict__ kT,
    const unsigned short* __restrict__ vB, const float* __restrict__ x,
    const float* __restrict__ gamma, float* __restrict__ out)
{
    __shared__ __align__(16) float El[BQ][68];            // E[n][m], 272B rows
    __shared__ __align__(16) unsigned short Pl[BQ * 64];  // P[n][m] bf16, 128B rows, XOR swz
    __shared__ float mrow[BQ], lrow[BQ], srow[BQ];

    const int tid  = threadIdx.x;
    const int lane = tid & 63;
    const int w    = tid >> 6;      // wave 0..3
    const int b    = blockIdx.y;
    const int n0   = blockIdx.x * BQ;
    const int ln   = lane & 15;
    const int g    = lane >> 4;     // 4-lane group 0..3

    // preload q B-frags (both 16-col n-tiles): qT[n][d], frag = 8 contiguous d
    bf16x8 qf0, qf1;
    {
        const unsigned short* qb = qT + ((size_t)b * NPX + n0) * 32 + g * 8;
        qf0 = *(const bf16x8*)(qb + (size_t)ln * 32);
        qf1 = *(const bf16x8*)(qb + (size_t)(ln + 16) * 32);
    }
    if (tid < BQ) { mrow[tid] = -INFINITY; lrow[tid] = 0.f; srow[tid] = 0.f; }

    const int r = tid >> 3;         // softmax row 0..31
    const int j = tid & 7;          // 8 lanes per row

    f32x4 acc[4][2];
#pragma unroll
    for (int ct = 0; ct < 4; ++ct)
#pragma unroll
        for (int t = 0; t < 2; ++t)
            acc[ct][t] = (f32x4){0.f, 0.f, 0.f, 0.f};

    const unsigned short* kTb = kT + (size_t)b * NPX * 32;
    const unsigned short* vb  = vB + ((size_t)(b * CCH) + w * 64) * NPX;

    for (int mb = 0; mb < NPX / BM; ++mb) {
        const int m0 = mb * BM;

        // ---- E phase: wave w computes E^T m-rows [w*16, w*16+16) x all 32 n
        const bf16x8 ka = *(const bf16x8*)(kTb + (size_t)(m0 + w * 16 + ln) * 32 + g * 8);
        f32x4 e0 = (f32x4){0.f, 0.f, 0.f, 0.f};
        f32x4 e1 = (f32x4){0.f, 0.f, 0.f, 0.f};
        e0 = __builtin_amdgcn_mfma_f32_16x16x32_bf16(ka, qf0, e0, 0, 0, 0);
        e1 = __builtin_amdgcn_mfma_f32_16x16x32_bf16(ka, qf1, e1, 0, 0, 0);
        // D rows m'=4g+reg, cols n'=ln  ->  El[n][w*16+4g+reg]
        *(f32x4*)&El[ln][w * 16 + g * 4]      = e0;
        *(f32x4*)&El[ln + 16][w * 16 + g * 4] = e1;
        __syncthreads();   // B1: E complete, mrow/lrow visible

        // ---- softmax (row r, lanes j*8..j*8+7 of the 64 keys)
        float ev[8];
        *(f32x4*)&ev[0] = *(const f32x4*)&El[r][8 * j];
        *(f32x4*)&ev[4] = *(const f32x4*)&El[r][8 * j + 4];
        float lm = fmaxf(fmaxf(fmaxf(ev[0], ev[1]), fmaxf(ev[2], ev[3])),
                         fmaxf(fmaxf(ev[4], ev[5]), fmaxf(ev[6], ev[7])));
        lm = fmaxf(lm, __shfl_xor(lm, 1));
        lm = fmaxf(lm, __shfl_xor(lm, 2));
        lm = fmaxf(lm, __shfl_xor(lm, 4));
        const float mold = mrow[r];          // same-wave lockstep vs j==0 write below
        const float mnew = fmaxf(mold, lm);
        float pv[8], ps = 0.f;
#pragma unroll
        for (int i = 0; i < 8; ++i) { pv[i] = __expf(ev[i] - mnew); ps += pv[i]; }
        ps += __shfl_xor(ps, 1);
        ps += __shfl_xor(ps, 2);
        ps += __shfl_xor(ps, 4);
        unsigned pu[4];
#pragma unroll
        for (int h = 0; h < 4; ++h)
            pu[h] = (unsigned)f2bf(pv[2 * h]) | ((unsigned)f2bf(pv[2 * h + 1]) << 16);
        const unsigned wb = (unsigned)r * 128u + (((unsigned)j * 16u) ^ (((unsigned)r & 7u) << 4));
        *(u32x4*)((char*)Pl + wb) = (u32x4){pu[0], pu[1], pu[2], pu[3]};
        if (j == 0) {
            const float sc = __expf(mold - mnew);
            srow[r] = sc;
            lrow[r] = lrow[r] * sc + ps;
            mrow[r] = mnew;
        }
        __syncthreads();   // B2: P + srow ready

        // ---- PV: rescale accs, then 16 mfma (4 c-tiles x 2 n-tiles x 2 k-slices)
        const float sc0 = srow[ln], sc1 = srow[16 + ln];
#pragma unroll
        for (int ct = 0; ct < 4; ++ct)
#pragma unroll
            for (int rr = 0; rr < 4; ++rr) {
                acc[ct][0][rr] *= sc0;
                acc[ct][1][rr] *= sc1;
            }
        bf16x8 pf[2][2];
#pragma unroll
        for (int t = 0; t < 2; ++t)
#pragma unroll
            for (int s = 0; s < 2; ++s) {
                const unsigned rb = (unsigned)(t * 16 + ln) * 128u
                                  + (((unsigned)(s * 64 + g * 16)) ^ (((unsigned)ln & 7u) << 4));
                pf[t][s] = *(const bf16x8*)((const char*)Pl + rb);
            }
#pragma unroll
        for (int ct = 0; ct < 4; ++ct) {
            const unsigned short* vrow = vb + (size_t)(ct * 16 + ln) * NPX + m0 + g * 8;
            const bf16x8 va0 = *(const bf16x8*)(vrow);        // k-slice 0: m0+8g+i
            const bf16x8 va1 = *(const bf16x8*)(vrow + 32);   // k-slice 1: m0+32+8g+i
            acc[ct][0] = __builtin_amdgcn_mfma_f32_16x16x32_bf16(va0, pf[0][0], acc[ct][0], 0, 0, 0);
            acc[ct][0] = __builtin_amdgcn_mfma_f32_16x16x32_bf16(va1, pf[0][1], acc[ct][0], 0, 0, 0);
            acc[ct][1] = __builtin_amdgcn_mfma_f32_16x16x32_bf16(va0, pf[1][0], acc[ct][1], 0, 0, 0);
            acc[ct][1] = __builtin_amdgcn_mfma_f32_16x16x32_bf16(va1, pf[1][1], acc[ct][1], 0, 0, 0);
        }
    }

    // ---- epilogue: out = gamma * acc/l + x
    const float gm   = gamma[0];
    const float inv0 = 1.f / lrow[ln];
    const float inv1 = 1.f / lrow[16 + ln];
#pragma unroll
    for (int ct = 0; ct < 4; ++ct) {
        const int c = w * 64 + ct * 16 + g * 4;
#pragma unroll
        for (int t = 0; t < 2; ++t) {
            const float iv = t ? inv1 : inv0;
            const size_t idx0 = ((size_t)(b * CCH + c)) * NPX + n0 + t * 16 + ln;
#pragma unroll
            for (int rr = 0; rr < 4; ++rr) {
                const size_t idx = idx0 + (size_t)rr * NPX;
                out[idx] = gm * acc[ct][t][rr] * iv + x[idx];
            }
        }
    }
}

extern "C" void kernel_launch(void* const* d_in, const int* in_sizes, int n_in,
                              void* d_out, int out_size, void* d_ws, size_t ws_size,
                              hipStream_t stream)
{
    const float* x  = (const float*)d_in[0];
    const float* Wq = (const float*)d_in[1];
    const float* bq = (const float*)d_in[2];
    const float* Wk = (const float*)d_in[3];
    const float* bk = (const float*)d_in[4];
    const float* Wv = (const float*)d_in[5];
    const float* bv = (const float*)d_in[6];
    const float* gm = (const float*)d_in[7];
    float* out = (float*)d_out;
    unsigned short* ws = (unsigned short*)d_ws;  // 10 MB: qT(1) + kT(1) + v(8)

    dim3 pgrid(NPX / 1024, 320 / 16, NB);
    proj_kernel<<<pgrid, 256, 0, stream>>>(x, Wq, bq, Wk, bk, Wv, bv, ws);

    const unsigned short* qT = ws;
    const unsigned short* kT = ws + (size_t)NB * NPX * 32;
    const unsigned short* vB = ws + (size_t)2 * NB * NPX * 32;

    dim3 agrid(NPX / BQ, NB);
    attn_kernel<<<agrid, 256, 0, stream>>>(qT, kT, vB, x, gm, out);
}

// Round 7
// 218.943 us; speedup vs baseline: 1.1112x; 1.1112x over previous
//
#include <hip/hip_runtime.h>
#include <cstddef>
#include <cstdint>

#define CCH 256   // channels
#define DQK 32    // q/k channels
#define NPX 4096  // H*W
#define BQ  32    // query tile per block
#define BM  64    // key tile per iteration
#define NB  4     // batch

typedef __attribute__((ext_vector_type(8))) short bf16x8;   // 8 bf16 = 4 VGPR (MFMA A/B frag)
typedef __attribute__((ext_vector_type(4))) float f32x4;    // MFMA C/D frag
typedef __attribute__((ext_vector_type(4))) unsigned int u32x4;

__device__ inline unsigned short f2bf(float f) {            // RNE float->bf16
    unsigned u = __builtin_bit_cast(unsigned, f);
    u += 0x7FFFu + ((u >> 16) & 1u);
    return (unsigned short)(u >> 16);
}
__device__ inline float bf2f(unsigned short h) {
    unsigned u = (unsigned)h << 16;
    return __builtin_bit_cast(float, u);
}

// ---------------------------------------------------------------------------
// Fused q/k/v 1x1-conv projection -> bf16 outputs in ws (unchanged from R6).
// ---------------------------------------------------------------------------
__global__ __launch_bounds__(256) void proj_kernel(
    const float* __restrict__ x,
    const float* __restrict__ Wq, const float* __restrict__ bq,
    const float* __restrict__ Wk, const float* __restrict__ bk,
    const float* __restrict__ Wv, const float* __restrict__ bv,
    unsigned short* __restrict__ ws)
{
    const int tid = threadIdx.x;
    const int b   = blockIdx.z;
    const int o0  = blockIdx.y * 16;
    const int nb  = blockIdx.x * 1024 + tid * 4;

    const float* Wbase;
    const float* bbase;
    if (o0 < 32)      { Wbase = Wq + o0 * CCH;        bbase = bq + o0; }
    else if (o0 < 64) { Wbase = Wk + (o0 - 32) * CCH; bbase = bk + (o0 - 32); }
    else              { Wbase = Wv + (o0 - 64) * CCH; bbase = bv + (o0 - 64); }

    float4 acc[16];
#pragma unroll
    for (int ol = 0; ol < 16; ++ol) {
        float bb = bbase[ol];
        acc[ol] = make_float4(bb, bb, bb, bb);
    }

    const float* xp = x + ((size_t)b * CCH) * NPX + nb;
#pragma unroll 4
    for (int c = 0; c < CCH; ++c) {
        float4 x4 = *(const float4*)(xp + (size_t)c * NPX);
#pragma unroll
        for (int ol = 0; ol < 16; ++ol) {
            float w = Wbase[ol * CCH + c];
            acc[ol].x += w * x4.x;
            acc[ol].y += w * x4.y;
            acc[ol].z += w * x4.z;
            acc[ol].w += w * x4.w;
        }
    }

    if (o0 < 64) {
        unsigned short* dstT = ws + ((o0 < 32) ? (size_t)0 : (size_t)NB * NPX * 32);
        const int col0 = o0 & 16;
        unsigned short* base = dstT + ((size_t)b * NPX + nb) * 32 + col0;
#pragma unroll
        for (int p = 0; p < 4; ++p) {
            unsigned u[8];
#pragma unroll
            for (int h = 0; h < 8; ++h) {
                const float* a0 = (const float*)&acc[2 * h];
                const float* a1 = (const float*)&acc[2 * h + 1];
                u[h] = (unsigned)f2bf(a0[p]) | ((unsigned)f2bf(a1[p]) << 16);
            }
            u32x4* dp = (u32x4*)(base + (size_t)p * 32);
            dp[0] = (u32x4){u[0], u[1], u[2], u[3]};
            dp[1] = (u32x4){u[4], u[5], u[6], u[7]};
        }
    } else {
        unsigned short* vbase = ws + (size_t)2 * NB * NPX * 32;
        const int c0 = o0 - 64;
#pragma unroll
        for (int ol = 0; ol < 16; ++ol) {
            unsigned lo = (unsigned)f2bf(acc[ol].x) | ((unsigned)f2bf(acc[ol].y) << 16);
            unsigned hi = (unsigned)f2bf(acc[ol].z) | ((unsigned)f2bf(acc[ol].w) << 16);
            uint2* dp = (uint2*)(vbase + ((size_t)(b * CCH + c0 + ol)) * NPX + nb);
            *dp = make_uint2(lo, hi);
        }
    }
}

// ---------------------------------------------------------------------------
// Flash attention, bf16 MFMA, key-sliced (flash-decode style).
// blockIdx.z = key slice s of ns; keys [s*NPX/ns, (s+1)*NPX/ns).
// If opart != null: write raw partial acc (bf16) + per-query m,l; else full
// epilogue (gamma*acc/l + x) directly (ns==1 fallback).
// ---------------------------------------------------------------------------
__global__ __launch_bounds__(256) void attn_kernel(
    const unsigned short* __restrict__ qT, const unsigned short* __restrict__ kT,
    const unsigned short* __restrict__ vB, const float* __restrict__ x,
    const float* __restrict__ gamma, float* __restrict__ out,
    unsigned short* __restrict__ opart, float* __restrict__ mlm,
    float* __restrict__ mll)
{
    __shared__ __align__(16) float El[BQ][68];            // E[n][m], 272B rows
    __shared__ __align__(16) unsigned short Pl[BQ * 64];  // P[n][m] bf16, XOR swz
    __shared__ float mrow[BQ], lrow[BQ], srow[BQ];

    const int tid  = threadIdx.x;
    const int lane = tid & 63;
    const int w    = tid >> 6;      // wave 0..3
    const int b    = blockIdx.y;
    const int n0   = blockIdx.x * BQ;
    const int s    = blockIdx.z;
    const int ns   = gridDim.z;
    const int ln   = lane & 15;
    const int g    = lane >> 4;     // 4-lane group 0..3

    bf16x8 qf0, qf1;
    {
        const unsigned short* qb = qT + ((size_t)b * NPX + n0) * 32 + g * 8;
        qf0 = *(const bf16x8*)(qb + (size_t)ln * 32);
        qf1 = *(const bf16x8*)(qb + (size_t)(ln + 16) * 32);
    }
    if (tid < BQ) { mrow[tid] = -INFINITY; lrow[tid] = 0.f; srow[tid] = 0.f; }

    const int r = tid >> 3;         // softmax row 0..31
    const int j = tid & 7;          // 8 lanes per row

    f32x4 acc[4][2];
#pragma unroll
    for (int ct = 0; ct < 4; ++ct)
#pragma unroll
        for (int t = 0; t < 2; ++t)
            acc[ct][t] = (f32x4){0.f, 0.f, 0.f, 0.f};

    const unsigned short* kTb = kT + (size_t)b * NPX * 32;
    const unsigned short* vb  = vB + ((size_t)(b * CCH) + w * 64) * NPX;

    const int kbase = s * (NPX / ns);
    const int iters = NPX / (ns * BM);

    for (int mb = 0; mb < iters; ++mb) {
        const int m0 = kbase + mb * BM;

        // ---- E phase
        const bf16x8 ka = *(const bf16x8*)(kTb + (size_t)(m0 + w * 16 + ln) * 32 + g * 8);
        f32x4 e0 = (f32x4){0.f, 0.f, 0.f, 0.f};
        f32x4 e1 = (f32x4){0.f, 0.f, 0.f, 0.f};
        e0 = __builtin_amdgcn_mfma_f32_16x16x32_bf16(ka, qf0, e0, 0, 0, 0);
        e1 = __builtin_amdgcn_mfma_f32_16x16x32_bf16(ka, qf1, e1, 0, 0, 0);
        *(f32x4*)&El[ln][w * 16 + g * 4]      = e0;
        *(f32x4*)&El[ln + 16][w * 16 + g * 4] = e1;
        __syncthreads();   // B1

        // ---- softmax (row r, 8 keys per lane)
        float ev[8];
        *(f32x4*)&ev[0] = *(const f32x4*)&El[r][8 * j];
        *(f32x4*)&ev[4] = *(const f32x4*)&El[r][8 * j + 4];
        float lm = fmaxf(fmaxf(fmaxf(ev[0], ev[1]), fmaxf(ev[2], ev[3])),
                         fmaxf(fmaxf(ev[4], ev[5]), fmaxf(ev[6], ev[7])));
        lm = fmaxf(lm, __shfl_xor(lm, 1));
        lm = fmaxf(lm, __shfl_xor(lm, 2));
        lm = fmaxf(lm, __shfl_xor(lm, 4));
        const float mold = mrow[r];
        const float mnew = fmaxf(mold, lm);
        float pv[8], ps = 0.f;
#pragma unroll
        for (int i = 0; i < 8; ++i) { pv[i] = __expf(ev[i] - mnew); ps += pv[i]; }
        ps += __shfl_xor(ps, 1);
        ps += __shfl_xor(ps, 2);
        ps += __shfl_xor(ps, 4);
        unsigned pu[4];
#pragma unroll
        for (int h = 0; h < 4; ++h)
            pu[h] = (unsigned)f2bf(pv[2 * h]) | ((unsigned)f2bf(pv[2 * h + 1]) << 16);
        const unsigned wb = (unsigned)r * 128u + (((unsigned)j * 16u) ^ (((unsigned)r & 7u) << 4));
        *(u32x4*)((char*)Pl + wb) = (u32x4){pu[0], pu[1], pu[2], pu[3]};
        if (j == 0) {
            const float sc = __expf(mold - mnew);
            srow[r] = sc;
            lrow[r] = lrow[r] * sc + ps;
            mrow[r] = mnew;
        }
        __syncthreads();   // B2

        // ---- PV
        const float sc0 = srow[ln], sc1 = srow[16 + ln];
#pragma unroll
        for (int ct = 0; ct < 4; ++ct)
#pragma unroll
            for (int rr = 0; rr < 4; ++rr) {
                acc[ct][0][rr] *= sc0;
                acc[ct][1][rr] *= sc1;
            }
        bf16x8 pf[2][2];
#pragma unroll
        for (int t = 0; t < 2; ++t)
#pragma unroll
            for (int ss = 0; ss < 2; ++ss) {
                const unsigned rb = (unsigned)(t * 16 + ln) * 128u
                                  + (((unsigned)(ss * 64 + g * 16)) ^ (((unsigned)ln & 7u) << 4));
                pf[t][ss] = *(const bf16x8*)((const char*)Pl + rb);
            }
#pragma unroll
        for (int ct = 0; ct < 4; ++ct) {
            const unsigned short* vrow = vb + (size_t)(ct * 16 + ln) * NPX + m0 + g * 8;
            const bf16x8 va0 = *(const bf16x8*)(vrow);
            const bf16x8 va1 = *(const bf16x8*)(vrow + 32);
            acc[ct][0] = __builtin_amdgcn_mfma_f32_16x16x32_bf16(va0, pf[0][0], acc[ct][0], 0, 0, 0);
            acc[ct][0] = __builtin_amdgcn_mfma_f32_16x16x32_bf16(va1, pf[0][1], acc[ct][0], 0, 0, 0);
            acc[ct][1] = __builtin_amdgcn_mfma_f32_16x16x32_bf16(va0, pf[1][0], acc[ct][1], 0, 0, 0);
            acc[ct][1] = __builtin_amdgcn_mfma_f32_16x16x32_bf16(va1, pf[1][1], acc[ct][1], 0, 0, 0);
        }
    }

    if (opart) {
        // partial epilogue: raw acc (bf16) + per-query m,l
        const size_t sb = (size_t)(s * NB + b);
#pragma unroll
        for (int ct = 0; ct < 4; ++ct) {
            const int c = w * 64 + ct * 16 + g * 4;
#pragma unroll
            for (int t = 0; t < 2; ++t) {
                const size_t idx0 = (sb * CCH + c) * NPX + n0 + t * 16 + ln;
#pragma unroll
                for (int rr = 0; rr < 4; ++rr)
                    opart[idx0 + (size_t)rr * NPX] = f2bf(acc[ct][t][rr]);
            }
        }
        if (tid < BQ) {
            mlm[sb * NPX + n0 + tid] = mrow[tid];
            mll[sb * NPX + n0 + tid] = lrow[tid];
        }
    } else {
        // direct epilogue (ns==1 path)
        const float gm   = gamma[0];
        const float inv0 = 1.f / lrow[ln];
        const float inv1 = 1.f / lrow[16 + ln];
#pragma unroll
        for (int ct = 0; ct < 4; ++ct) {
            const int c = w * 64 + ct * 16 + g * 4;
#pragma unroll
            for (int t = 0; t < 2; ++t) {
                const float iv = t ? inv1 : inv0;
                const size_t idx0 = ((size_t)(b * CCH + c)) * NPX + n0 + t * 16 + ln;
#pragma unroll
                for (int rr = 0; rr < 4; ++rr) {
                    const size_t idx = idx0 + (size_t)rr * NPX;
                    out[idx] = gm * acc[ct][t][rr] * iv + x[idx];
                }
            }
        }
    }
}

// ---------------------------------------------------------------------------
// Combine: log-sum-exp merge of ns key-slice partials + gamma/residual.
// Thread handles 8 consecutive n of one (b,c) row.
// ---------------------------------------------------------------------------
__global__ __launch_bounds__(256) void combine_kernel(
    const unsigned short* __restrict__ opart,
    const float* __restrict__ mlm, const float* __restrict__ mll,
    const float* __restrict__ x, const float* __restrict__ gamma,
    float* __restrict__ out, int ns)
{
    const int idx = blockIdx.x * 256 + threadIdx.x;   // NB*CCH*512 threads
    const int bc  = idx >> 9;                          // b*CCH + c
    const int b   = bc / CCH;
    const int c   = bc - b * CCH;
    const int n0  = (idx & 511) * 8;

    float M[8];
#pragma unroll
    for (int i = 0; i < 8; ++i) M[i] = -INFINITY;
    for (int s = 0; s < ns; ++s) {
        const float* mp = mlm + ((size_t)(s * NB + b)) * NPX + n0;
#pragma unroll
        for (int i = 0; i < 8; ++i) M[i] = fmaxf(M[i], mp[i]);
    }

    float L[8], O[8];
#pragma unroll
    for (int i = 0; i < 8; ++i) { L[i] = 0.f; O[i] = 0.f; }
    for (int s = 0; s < ns; ++s) {
        const size_t sb = (size_t)(s * NB + b);
        const float* mp = mlm + sb * NPX + n0;
        const float* lp = mll + sb * NPX + n0;
        const bf16x8 v8 = *(const bf16x8*)(opart + (sb * CCH + c) * NPX + n0);
#pragma unroll
        for (int i = 0; i < 8; ++i) {
            const float wgt = __expf(mp[i] - M[i]);
            L[i] += wgt * lp[i];
            O[i] += wgt * bf2f((unsigned short)v8[i]);
        }
    }

    const float gm = gamma[0];
    const size_t xo = (size_t)bc * NPX + n0;
    float4 r0, r1;
    const float4 x0 = *(const float4*)(x + xo);
    const float4 x1 = *(const float4*)(x + xo + 4);
    r0.x = gm * O[0] / L[0] + x0.x;  r0.y = gm * O[1] / L[1] + x0.y;
    r0.z = gm * O[2] / L[2] + x0.z;  r0.w = gm * O[3] / L[3] + x0.w;
    r1.x = gm * O[4] / L[4] + x1.x;  r1.y = gm * O[5] / L[5] + x1.y;
    r1.z = gm * O[6] / L[6] + x1.z;  r1.w = gm * O[7] / L[7] + x1.w;
    *(float4*)(out + xo)     = r0;
    *(float4*)(out + xo + 4) = r1;
}

extern "C" void kernel_launch(void* const* d_in, const int* in_sizes, int n_in,
                              void* d_out, int out_size, void* d_ws, size_t ws_size,
                              hipStream_t stream)
{
    const float* x  = (const float*)d_in[0];
    const float* Wq = (const float*)d_in[1];
    const float* bq = (const float*)d_in[2];
    const float* Wk = (const float*)d_in[3];
    const float* bk = (const float*)d_in[4];
    const float* Wv = (const float*)d_in[5];
    const float* bv = (const float*)d_in[6];
    const float* gm = (const float*)d_in[7];
    float* out = (float*)d_out;
    unsigned short* ws = (unsigned short*)d_ws;

    const size_t qkvB   = (size_t)(2 * NB * NPX * 32 + NB * CCH * NPX) * 2;  // 10 MB
    const size_t partB  = (size_t)NB * CCH * NPX * 2;                        // 8 MB / slice
    const size_t mlB    = (size_t)2 * NB * NPX * 4;                          // 128 KB / slice
    int ns = 1;
    if      (ws_size >= qkvB + 4 * (partB + mlB)) ns = 4;
    else if (ws_size >= qkvB + 2 * (partB + mlB)) ns = 2;

    dim3 pgrid(NPX / 1024, 320 / 16, NB);
    proj_kernel<<<pgrid, 256, 0, stream>>>(x, Wq, bq, Wk, bk, Wv, bv, ws);

    const unsigned short* qT = ws;
    const unsigned short* kT = ws + (size_t)NB * NPX * 32;
    const unsigned short* vB = ws + (size_t)2 * NB * NPX * 32;

    if (ns > 1) {
        unsigned short* opart = ws + (size_t)2 * NB * NPX * 32 + (size_t)NB * CCH * NPX;
        float* mlm = (float*)(opart + (size_t)ns * NB * CCH * NPX);
        float* mll = mlm + (size_t)ns * NB * NPX;

        dim3 agrid(NPX / BQ, NB, ns);
        attn_kernel<<<agrid, 256, 0, stream>>>(qT, kT, vB, x, gm, out, opart, mlm, mll);

        const int cblocks = (NB * CCH * (NPX / 8)) / 256;
        combine_kernel<<<cblocks, 256, 0, stream>>>(opart, mlm, mll, x, gm, out, ns);
    } else {
        dim3 agrid(NPX / BQ, NB, 1);
        attn_kernel<<<agrid, 256, 0, stream>>>(qT, kT, vB, x, gm, out,
                                               nullptr, nullptr, nullptr);
    }
}